// Round 1
// baseline (513.317 us; speedup 1.0000x reference)
//
#include <hip/hip_runtime.h>

#define D 64
#define WAVE 64

// ---------------- K1: x_l = x@W_l + b_l ; x_r = x@W_r + b_r ----------------
// One wave per node (grid-stride). W_l, W_r staged in LDS (64x64 each).
// Lane d computes output dim d; x row broadcast via __shfl.
__global__ void transform_kernel(const float* __restrict__ x,
                                 const float* __restrict__ Wl,
                                 const float* __restrict__ bl,
                                 const float* __restrict__ Wr,
                                 const float* __restrict__ br,
                                 float* __restrict__ xl,
                                 float* __restrict__ xr,
                                 int n) {
    __shared__ float sWl[D * D];
    __shared__ float sWr[D * D];
    for (int i = threadIdx.x; i < D * D; i += blockDim.x) {
        sWl[i] = Wl[i];
        sWr[i] = Wr[i];
    }
    __syncthreads();
    const int lane = threadIdx.x & (WAVE - 1);
    const int wid = (blockIdx.x * blockDim.x + threadIdx.x) >> 6;
    const int nw = (gridDim.x * blockDim.x) >> 6;
    const float bll = bl[lane];
    const float brl = br[lane];
    for (int node = wid; node < n; node += nw) {
        const float xk = x[node * D + lane];
        float accl = bll, accr = brl;
#pragma unroll
        for (int k = 0; k < D; ++k) {
            const float xv = __shfl(xk, k, WAVE);
            accl = fmaf(xv, sWl[k * D + lane], accl);
            accr = fmaf(xv, sWr[k * D + lane], accr);
        }
        xl[node * D + lane] = accl;
        xr[node * D + lane] = accr;
    }
}

// ---------------- K2: per-edge logit e, p = exp(e), z[dst] += p ------------
// One wave per edge (grid-stride). Self loops are edges j in [E, E+N).
__global__ void edge_kernel(const int* __restrict__ ei,
                            const float* __restrict__ xl,
                            const float* __restrict__ xr,
                            const float* __restrict__ att,
                            float* __restrict__ p,
                            float* __restrict__ z,
                            int E_, int n) {
    const int lane = threadIdx.x & (WAVE - 1);
    const int wid = (blockIdx.x * blockDim.x + threadIdx.x) >> 6;
    const int nw = (gridDim.x * blockDim.x) >> 6;
    const int total = E_ + n;
    const float a = att[lane];
    for (int j = wid; j < total; j += nw) {
        int s, d;
        if (j < E_) {
            s = ei[j];
            d = ei[E_ + j];
        } else {
            s = j - E_;
            d = s;
        }
        float v = xl[s * D + lane] + xr[d * D + lane];
        v = (v > 0.f) ? v : 0.2f * v;
        float e = v * a;
#pragma unroll
        for (int off = 32; off; off >>= 1) e += __shfl_xor(e, off, WAVE);
        if (lane == 0) {
            const float pe = __expf(e);
            p[j] = pe;
            atomicAdd(&z[d], pe);
        }
    }
}

// ---------------- K3: out[dst] += (p/z[dst]) * x_l[src] --------------------
__global__ void scatter_kernel(const int* __restrict__ ei,
                               const float* __restrict__ xl,
                               const float* __restrict__ p,
                               const float* __restrict__ z,
                               float* __restrict__ out,
                               int E_, int n) {
    const int lane = threadIdx.x & (WAVE - 1);
    const int wid = (blockIdx.x * blockDim.x + threadIdx.x) >> 6;
    const int nw = (gridDim.x * blockDim.x) >> 6;
    const int total = E_ + n;
    for (int j = wid; j < total; j += nw) {
        int s, d;
        if (j < E_) {
            s = ei[j];
            d = ei[E_ + j];
        } else {
            s = j - E_;
            d = s;
        }
        const float alpha = p[j] / z[d];
        atomicAdd(&out[d * D + lane], alpha * xl[s * D + lane]);
    }
}

// ---------------- K4: out = LN(out + bias) * gamma + beta (in place) -------
__global__ void ln_kernel(float* __restrict__ out,
                          const float* __restrict__ bias,
                          const float* __restrict__ gamma,
                          const float* __restrict__ beta,
                          int n) {
    const int lane = threadIdx.x & (WAVE - 1);
    const int wid = (blockIdx.x * blockDim.x + threadIdx.x) >> 6;
    const int nw = (gridDim.x * blockDim.x) >> 6;
    const float bl = bias[lane];
    const float gl = gamma[lane];
    const float be = beta[lane];
    for (int node = wid; node < n; node += nw) {
        float v = out[node * D + lane] + bl;
        float s = v;
#pragma unroll
        for (int off = 32; off; off >>= 1) s += __shfl_xor(s, off, WAVE);
        const float mu = s * (1.0f / D);
        const float dv = v - mu;
        float s2 = dv * dv;
#pragma unroll
        for (int off = 32; off; off >>= 1) s2 += __shfl_xor(s2, off, WAVE);
        const float var = s2 * (1.0f / D);
        const float rs = rsqrtf(var + 1e-5f);
        out[node * D + lane] = dv * rs * gl + be;
    }
}

extern "C" void kernel_launch(void* const* d_in, const int* in_sizes, int n_in,
                              void* d_out, int out_size, void* d_ws, size_t ws_size,
                              hipStream_t stream) {
    const float* x = (const float*)d_in[0];
    const int* ei = (const int*)d_in[1];
    const float* Wl = (const float*)d_in[2];
    const float* bl = (const float*)d_in[3];
    const float* Wr = (const float*)d_in[4];
    const float* br = (const float*)d_in[5];
    const float* att = (const float*)d_in[6];
    const float* bias = (const float*)d_in[7];
    const float* gamma = (const float*)d_in[8];
    const float* beta = (const float*)d_in[9];

    const int n = in_sizes[0] / D;        // 100000
    const int E_ = in_sizes[1] / 2;       // 1000000

    float* ws = (float*)d_ws;
    float* xl = ws;                       // n*D
    float* xr = xl + (size_t)n * D;       // n*D
    float* p = xr + (size_t)n * D;        // E_+n
    float* z = p + (size_t)(E_ + n);      // n
    float* out = (float*)d_out;           // n*D accumulated in place

    hipMemsetAsync(z, 0, (size_t)n * sizeof(float), stream);
    hipMemsetAsync(out, 0, (size_t)n * D * sizeof(float), stream);

    transform_kernel<<<1024, 256, 0, stream>>>(x, Wl, bl, Wr, br, xl, xr, n);
    edge_kernel<<<2048, 256, 0, stream>>>(ei, xl, xr, att, p, z, E_, n);
    scatter_kernel<<<2048, 256, 0, stream>>>(ei, xl, p, z, out, E_, n);
    ln_kernel<<<2048, 256, 0, stream>>>(out, bias, gamma, beta, n);
}

// Round 2
// 360.697 us; speedup vs baseline: 1.4231x; 1.4231x over previous
//
#include <hip/hip_runtime.h>

#define D 64
#define WAVE 64
#define SCAN_B 1024

// ---------------- K1: x_l = x@W_l + b_l ; x_r = x@W_r + b_r ----------------
__global__ void transform_kernel(const float* __restrict__ x,
                                 const float* __restrict__ Wl,
                                 const float* __restrict__ bl,
                                 const float* __restrict__ Wr,
                                 const float* __restrict__ br,
                                 float* __restrict__ xl,
                                 float* __restrict__ xr,
                                 int n) {
    __shared__ float sWl[D * D];
    __shared__ float sWr[D * D];
    for (int i = threadIdx.x; i < D * D; i += blockDim.x) {
        sWl[i] = Wl[i];
        sWr[i] = Wr[i];
    }
    __syncthreads();
    const int lane = threadIdx.x & (WAVE - 1);
    const int wid = (blockIdx.x * blockDim.x + threadIdx.x) >> 6;
    const int nw = (gridDim.x * blockDim.x) >> 6;
    const float bll = bl[lane];
    const float brl = br[lane];
    for (int node = wid; node < n; node += nw) {
        const float xk = x[node * D + lane];
        float accl = bll, accr = brl;
#pragma unroll
        for (int k = 0; k < D; ++k) {
            const float xv = __shfl(xk, k, WAVE);
            accl = fmaf(xv, sWl[k * D + lane], accl);
            accr = fmaf(xv, sWr[k * D + lane], accr);
        }
        xl[node * D + lane] = accl;
        xr[node * D + lane] = accr;
    }
}

// ---------------- CSR build: histogram of dst ------------------------------
__global__ void hist_kernel(const int* __restrict__ ei, int* __restrict__ cnt,
                            int E_) {
    const int stride = gridDim.x * blockDim.x;
    for (int j = blockIdx.x * blockDim.x + threadIdx.x; j < E_; j += stride)
        atomicAdd(&cnt[ei[E_ + j]], 1);
}

// Per-block inclusive scan of cnt -> cursor (local), block totals -> bsums
__global__ void scan_local(const int* __restrict__ cnt, int* __restrict__ cursor,
                           int* __restrict__ bsums, int n) {
    __shared__ int tmp[SCAN_B];
    const int t = threadIdx.x;
    const int gid = blockIdx.x * SCAN_B + t;
    const int v = (gid < n) ? cnt[gid] : 0;
    tmp[t] = v;
    __syncthreads();
    for (int off = 1; off < SCAN_B; off <<= 1) {
        int u = (t >= off) ? tmp[t - off] : 0;
        __syncthreads();
        tmp[t] += u;
        __syncthreads();
    }
    if (gid < n) cursor[gid] = tmp[t] - v;  // exclusive (block-local)
    if (t == SCAN_B - 1) bsums[blockIdx.x] = tmp[t];
}

__global__ void scan_tops(int* __restrict__ bsums, int nb) {
    if (blockIdx.x == 0 && threadIdx.x == 0) {
        int acc = 0;
        for (int i = 0; i < nb; ++i) {
            const int v = bsums[i];
            bsums[i] = acc;
            acc += v;
        }
    }
}

__global__ void scan_add(int* __restrict__ cursor, const int* __restrict__ bsums,
                         int n) {
    const int gid = blockIdx.x * blockDim.x + threadIdx.x;
    if (gid < n) cursor[gid] += bsums[gid >> 10];  // now = row start
}

// Fill CSR: esrc[row_start[dst] ... ] = src. Advances cursor to row end.
__global__ void fill_kernel(const int* __restrict__ ei, int* __restrict__ cursor,
                            int* __restrict__ esrc, int E_) {
    const int stride = gridDim.x * blockDim.x;
    for (int j = blockIdx.x * blockDim.x + threadIdx.x; j < E_; j += stride) {
        const int d = ei[E_ + j];
        const int pos = atomicAdd(&cursor[d], 1);
        esrc[pos] = ei[j];
    }
}

// ---------------- Fused: attention softmax + aggregate + bias + LN ---------
// One wave per node. After fill, cursor[node] = row_end; beg = end - cnt.
__global__ void fused_kernel(const int* __restrict__ esrc,
                             const int* __restrict__ cursor,
                             const int* __restrict__ cnt,
                             const float* __restrict__ xl,
                             const float* __restrict__ xr,
                             const float* __restrict__ att,
                             const float* __restrict__ bias,
                             const float* __restrict__ gamma,
                             const float* __restrict__ beta,
                             float* __restrict__ out, int n) {
    const int lane = threadIdx.x & (WAVE - 1);
    const int wid = (blockIdx.x * blockDim.x + threadIdx.x) >> 6;
    const int nw = (gridDim.x * blockDim.x) >> 6;
    const float a = att[lane];
    const float bl = bias[lane];
    const float gl = gamma[lane];
    const float be = beta[lane];
    for (int node = wid; node < n; node += nw) {
        const float xrv = xr[node * D + lane];
        // self loop
        const float xlv = xl[node * D + lane];
        float v = xlv + xrv;
        v = (v > 0.f) ? v : 0.2f * v;
        float e = v * a;
#pragma unroll
        for (int off = 32; off; off >>= 1) e += __shfl_xor(e, off, WAVE);
        float p = __expf(e);
        float z = p;
        float acc = p * xlv;
        // in-edges
        const int c = cnt[node];
        const int beg = cursor[node] - c;
        for (int k = 0; k < c; ++k) {
            const int s = esrc[beg + k];
            const float xls = xl[s * D + lane];
            float v2 = xls + xrv;
            v2 = (v2 > 0.f) ? v2 : 0.2f * v2;
            float e2 = v2 * a;
#pragma unroll
            for (int off = 32; off; off >>= 1) e2 += __shfl_xor(e2, off, WAVE);
            const float p2 = __expf(e2);
            z += p2;
            acc = fmaf(p2, xls, acc);
        }
        // bias + LayerNorm
        float o = acc / z + bl;
        float s1 = o;
#pragma unroll
        for (int off = 32; off; off >>= 1) s1 += __shfl_xor(s1, off, WAVE);
        const float mu = s1 * (1.0f / D);
        const float dv = o - mu;
        float s2 = dv * dv;
#pragma unroll
        for (int off = 32; off; off >>= 1) s2 += __shfl_xor(s2, off, WAVE);
        const float var = s2 * (1.0f / D);
        const float rs = rsqrtf(var + 1e-5f);
        out[node * D + lane] = dv * rs * gl + be;
    }
}

extern "C" void kernel_launch(void* const* d_in, const int* in_sizes, int n_in,
                              void* d_out, int out_size, void* d_ws, size_t ws_size,
                              hipStream_t stream) {
    const float* x = (const float*)d_in[0];
    const int* ei = (const int*)d_in[1];
    const float* Wl = (const float*)d_in[2];
    const float* bl = (const float*)d_in[3];
    const float* Wr = (const float*)d_in[4];
    const float* br = (const float*)d_in[5];
    const float* att = (const float*)d_in[6];
    const float* bias = (const float*)d_in[7];
    const float* gamma = (const float*)d_in[8];
    const float* beta = (const float*)d_in[9];

    const int n = in_sizes[0] / D;   // 100000
    const int E_ = in_sizes[1] / 2;  // 1000000
    const int nb = (n + SCAN_B - 1) / SCAN_B;

    char* ws = (char*)d_ws;
    float* xl = (float*)ws;                       // n*D
    float* xr = xl + (size_t)n * D;               // n*D
    int* cnt = (int*)(xr + (size_t)n * D);        // n
    int* cursor = cnt + n;                        // n
    int* bsums = cursor + n;                      // nb
    int* esrc = bsums + ((nb + 63) & ~63);        // E_

    hipMemsetAsync(cnt, 0, (size_t)n * sizeof(int), stream);

    transform_kernel<<<1024, 256, 0, stream>>>(x, Wl, bl, Wr, br, xl, xr, n);
    hist_kernel<<<1024, 256, 0, stream>>>(ei, cnt, E_);
    scan_local<<<nb, SCAN_B, 0, stream>>>(cnt, cursor, bsums, n);
    scan_tops<<<1, 64, 0, stream>>>(bsums, nb);
    scan_add<<<(n + 255) / 256, 256, 0, stream>>>(cursor, bsums, n);
    fill_kernel<<<1024, 256, 0, stream>>>(ei, cursor, esrc, E_);
    fused_kernel<<<2048, 256, 0, stream>>>(esrc, cursor, cnt, xl, xr, att,
                                           bias, gamma, beta, (float*)d_out, n);
}

// Round 3
// 333.970 us; speedup vs baseline: 1.5370x; 1.0800x over previous
//
#include <hip/hip_runtime.h>

#define D 64
#define WAVE 64
#define SCAN_B 1024

// ------------- K1: transform (blocks [0,tblocks)) + dst histogram ----------
__global__ void transform_hist_kernel(const float* __restrict__ x,
                                      const float* __restrict__ Wl,
                                      const float* __restrict__ bl,
                                      const float* __restrict__ Wr,
                                      const float* __restrict__ br,
                                      float* __restrict__ xl,
                                      float* __restrict__ xr,
                                      const int* __restrict__ ei,
                                      int* __restrict__ cnt,
                                      int n, int E_, int tblocks) {
    if ((int)blockIdx.x < tblocks) {
        __shared__ float sWl[D * D];
        __shared__ float sWr[D * D];
        for (int i = threadIdx.x; i < D * D; i += blockDim.x) {
            sWl[i] = Wl[i];
            sWr[i] = Wr[i];
        }
        __syncthreads();
        const int lane = threadIdx.x & (WAVE - 1);
        const int wid = (blockIdx.x * blockDim.x + threadIdx.x) >> 6;
        const int nw = (tblocks * blockDim.x) >> 6;
        const float bll = bl[lane];
        const float brl = br[lane];
        for (int node = wid; node < n; node += nw) {
            const float xk = x[node * D + lane];
            float accl = bll, accr = brl;
#pragma unroll
            for (int k = 0; k < D; ++k) {
                const float xv = __shfl(xk, k, WAVE);
                accl = fmaf(xv, sWl[k * D + lane], accl);
                accr = fmaf(xv, sWr[k * D + lane], accr);
            }
            xl[node * D + lane] = accl;
            xr[node * D + lane] = accr;
        }
    } else {
        const int tid = (blockIdx.x - tblocks) * blockDim.x + threadIdx.x;
        const int stride = (gridDim.x - tblocks) * blockDim.x;
        for (int j = tid; j < E_; j += stride)
            atomicAdd(&cnt[ei[E_ + j]], 1);
    }
}

// ------------- scan: per-block exclusive scan + block sums -----------------
__global__ void scan_local(const int* __restrict__ cnt, int* __restrict__ cursor,
                           int* __restrict__ bsums, int n) {
    __shared__ int tmp[SCAN_B];
    const int t = threadIdx.x;
    const int gid = blockIdx.x * SCAN_B + t;
    const int v = (gid < n) ? cnt[gid] : 0;
    tmp[t] = v;
    __syncthreads();
    for (int off = 1; off < SCAN_B; off <<= 1) {
        int u = (t >= off) ? tmp[t - off] : 0;
        __syncthreads();
        tmp[t] += u;
        __syncthreads();
    }
    if (gid < n) cursor[gid] = tmp[t] - v;
    if (t == SCAN_B - 1) bsums[blockIdx.x] = tmp[t];
}

// one block, parallel exclusive scan of block sums (nb <= 1024)
__global__ void scan_tops(int* __restrict__ bsums, int nb) {
    __shared__ int tmp[SCAN_B];
    const int t = threadIdx.x;
    const int v = (t < nb) ? bsums[t] : 0;
    tmp[t] = v;
    __syncthreads();
    for (int off = 1; off < SCAN_B; off <<= 1) {
        int u = (t >= off) ? tmp[t - off] : 0;
        __syncthreads();
        tmp[t] += u;
        __syncthreads();
    }
    if (t < nb) bsums[t] = tmp[t] - v;  // exclusive
}

__global__ void scan_add(int* __restrict__ cursor, const int* __restrict__ bsums,
                         int n) {
    const int gid = blockIdx.x * blockDim.x + threadIdx.x;
    if (gid < n) cursor[gid] += bsums[gid >> 10];
}

// ------------- fill CSR: esrc[pos] = src, cursor -> row end ----------------
__global__ void fill_kernel(const int* __restrict__ ei, int* __restrict__ cursor,
                            int* __restrict__ esrc, int E_) {
    const int stride = gridDim.x * blockDim.x;
    for (int j = blockIdx.x * blockDim.x + threadIdx.x; j < E_; j += stride) {
        const int d = ei[E_ + j];
        const int pos = atomicAdd(&cursor[d], 1);
        esrc[pos] = ei[j];
    }
}

// ------------- fused: softmax-attention aggregate + bias + LN --------------
__global__ __launch_bounds__(256) void fused_kernel(
    const int* __restrict__ esrc, const int* __restrict__ cursor,
    const int* __restrict__ cnt, const float* __restrict__ xl,
    const float* __restrict__ xr, const float* __restrict__ att,
    const float* __restrict__ bias, const float* __restrict__ gamma,
    const float* __restrict__ beta, float* __restrict__ out, int n) {
    const int lane = threadIdx.x & (WAVE - 1);
    const int wid = (blockIdx.x * blockDim.x + threadIdx.x) >> 6;
    const int nw = (gridDim.x * blockDim.x) >> 6;
    const float a = att[lane];
    const float bl = bias[lane];
    const float gl = gamma[lane];
    const float be = beta[lane];
    for (int node = wid; node < n; node += nw) {
        const float xrv = xr[node * D + lane];
        const float xlv = xl[node * D + lane];
        // self loop
        float v = xlv + xrv;
        v = (v > 0.f) ? v : 0.2f * v;
        float e = v * a;
#pragma unroll
        for (int off = 32; off; off >>= 1) e += __shfl_xor(e, off, WAVE);
        float p = __expf(e);
        float z = p;
        float acc = p * xlv;
        // in-edges: preload up to 64 indices coalesced, broadcast via shfl
        const int c = cnt[node];
        const int beg = cursor[node] - c;
        for (int base = 0; base < c; base += WAVE) {
            const int cc = min(WAVE, c - base);
            const int myi = (lane < cc) ? esrc[beg + base + lane] : 0;
            int k = 0;
            for (; k + 4 <= cc; k += 4) {
                const int s0 = __shfl(myi, k, WAVE);
                const int s1 = __shfl(myi, k + 1, WAVE);
                const int s2 = __shfl(myi, k + 2, WAVE);
                const int s3 = __shfl(myi, k + 3, WAVE);
                const float x0 = xl[(size_t)s0 * D + lane];
                const float x1 = xl[(size_t)s1 * D + lane];
                const float x2 = xl[(size_t)s2 * D + lane];
                const float x3 = xl[(size_t)s3 * D + lane];
                float v0 = x0 + xrv; v0 = (v0 > 0.f) ? v0 : 0.2f * v0;
                float v1 = x1 + xrv; v1 = (v1 > 0.f) ? v1 : 0.2f * v1;
                float v2 = x2 + xrv; v2 = (v2 > 0.f) ? v2 : 0.2f * v2;
                float v3 = x3 + xrv; v3 = (v3 > 0.f) ? v3 : 0.2f * v3;
                float e0 = v0 * a, e1 = v1 * a, e2 = v2 * a, e3 = v3 * a;
#pragma unroll
                for (int off = 32; off; off >>= 1) {
                    e0 += __shfl_xor(e0, off, WAVE);
                    e1 += __shfl_xor(e1, off, WAVE);
                    e2 += __shfl_xor(e2, off, WAVE);
                    e3 += __shfl_xor(e3, off, WAVE);
                }
                const float p0 = __expf(e0);
                const float p1 = __expf(e1);
                const float p2 = __expf(e2);
                const float p3 = __expf(e3);
                z += (p0 + p1) + (p2 + p3);
                acc = fmaf(p0, x0, acc);
                acc = fmaf(p1, x1, acc);
                acc = fmaf(p2, x2, acc);
                acc = fmaf(p3, x3, acc);
            }
            for (; k < cc; ++k) {
                const int s = __shfl(myi, k, WAVE);
                const float xs = xl[(size_t)s * D + lane];
                float vv = xs + xrv;
                vv = (vv > 0.f) ? vv : 0.2f * vv;
                float ee = vv * a;
#pragma unroll
                for (int off = 32; off; off >>= 1) ee += __shfl_xor(ee, off, WAVE);
                const float pp = __expf(ee);
                z += pp;
                acc = fmaf(pp, xs, acc);
            }
        }
        // bias + LayerNorm
        float o = acc / z + bl;
        float s1 = o;
#pragma unroll
        for (int off = 32; off; off >>= 1) s1 += __shfl_xor(s1, off, WAVE);
        const float mu = s1 * (1.0f / D);
        const float dv = o - mu;
        float s2 = dv * dv;
#pragma unroll
        for (int off = 32; off; off >>= 1) s2 += __shfl_xor(s2, off, WAVE);
        const float var = s2 * (1.0f / D);
        const float rs = rsqrtf(var + 1e-5f);
        out[node * D + lane] = dv * rs * gl + be;
    }
}

extern "C" void kernel_launch(void* const* d_in, const int* in_sizes, int n_in,
                              void* d_out, int out_size, void* d_ws, size_t ws_size,
                              hipStream_t stream) {
    const float* x = (const float*)d_in[0];
    const int* ei = (const int*)d_in[1];
    const float* Wl = (const float*)d_in[2];
    const float* bl = (const float*)d_in[3];
    const float* Wr = (const float*)d_in[4];
    const float* br = (const float*)d_in[5];
    const float* att = (const float*)d_in[6];
    const float* bias = (const float*)d_in[7];
    const float* gamma = (const float*)d_in[8];
    const float* beta = (const float*)d_in[9];

    const int n = in_sizes[0] / D;   // 100000
    const int E_ = in_sizes[1] / 2;  // 1000000
    const int nb = (n + SCAN_B - 1) / SCAN_B;

    char* ws = (char*)d_ws;
    float* xl = (float*)ws;                       // n*D
    float* xr = xl + (size_t)n * D;               // n*D
    int* cnt = (int*)(xr + (size_t)n * D);        // n
    int* cursor = cnt + n;                        // n
    int* bsums = cursor + n;                      // nb
    int* esrc = bsums + ((nb + 63) & ~63);        // E_

    hipMemsetAsync(cnt, 0, (size_t)n * sizeof(int), stream);

    transform_hist_kernel<<<1536, 256, 0, stream>>>(x, Wl, bl, Wr, br, xl, xr,
                                                    ei, cnt, n, E_, 1024);
    scan_local<<<nb, SCAN_B, 0, stream>>>(cnt, cursor, bsums, n);
    scan_tops<<<1, SCAN_B, 0, stream>>>(bsums, nb);
    scan_add<<<(n + 255) / 256, 256, 0, stream>>>(cursor, bsums, n);
    fill_kernel<<<2048, 256, 0, stream>>>(ei, cursor, esrc, E_);
    fused_kernel<<<2048, 256, 0, stream>>>(esrc, cursor, cnt, xl, xr, att,
                                           bias, gamma, beta, (float*)d_out, n);
}

// Round 4
// 287.619 us; speedup vs baseline: 1.7847x; 1.1612x over previous
//
#include <hip/hip_runtime.h>
#include <hip/hip_bf16.h>

#define D 64
#define WAVE 64
#define SCAN_B 1024
#define NB 8

// ------------- K1: transform (blocks [0,tblocks)) + dst histogram ----------
// Transform: 8 nodes per wave so each LDS weight read is reused 8x.
// xl is stored ONLY as bf16 (consumer = attention gather); xr stays fp32.
__global__ __launch_bounds__(256) void transform_hist_kernel(
    const float* __restrict__ x, const float* __restrict__ Wl,
    const float* __restrict__ bl, const float* __restrict__ Wr,
    const float* __restrict__ br, __hip_bfloat16* __restrict__ xlb,
    float* __restrict__ xr, const int* __restrict__ ei,
    int* __restrict__ cnt, int n, int E_, int tblocks) {
    __shared__ float sWl[D * D];
    __shared__ float sWr[D * D];
    if ((int)blockIdx.x < tblocks) {
        for (int i = threadIdx.x; i < D * D; i += blockDim.x) {
            sWl[i] = Wl[i];
            sWr[i] = Wr[i];
        }
        __syncthreads();
        const int lane = threadIdx.x & (WAVE - 1);
        const int wid = (blockIdx.x * blockDim.x + threadIdx.x) >> 6;
        const int nw = (tblocks * blockDim.x) >> 6;
        const float bll = bl[lane];
        const float brl = br[lane];
        const int ngrp = (n + NB - 1) / NB;
        for (int g = wid; g < ngrp; g += nw) {
            const int node0 = g * NB;
            float xk[NB], accl[NB], accr[NB];
#pragma unroll
            for (int t = 0; t < NB; ++t) {
                const int nd = min(node0 + t, n - 1);
                xk[t] = x[(size_t)nd * D + lane];
                accl[t] = bll;
                accr[t] = brl;
            }
#pragma unroll 4
            for (int k = 0; k < D; ++k) {
                const float wl = sWl[k * D + lane];
                const float wr = sWr[k * D + lane];
#pragma unroll
                for (int t = 0; t < NB; ++t) {
                    const float xv = __shfl(xk[t], k, WAVE);
                    accl[t] = fmaf(xv, wl, accl[t]);
                    accr[t] = fmaf(xv, wr, accr[t]);
                }
            }
#pragma unroll
            for (int t = 0; t < NB; ++t) {
                if (node0 + t < n) {
                    const size_t off = (size_t)(node0 + t) * D + lane;
                    xlb[off] = __float2bfloat16(accl[t]);
                    xr[off] = accr[t];
                }
            }
        }
    } else {
        const int tid = (blockIdx.x - tblocks) * blockDim.x + threadIdx.x;
        const int stride = (gridDim.x - tblocks) * blockDim.x;
        for (int j = tid; j < E_; j += stride)
            atomicAdd(&cnt[ei[E_ + j]], 1);
    }
}

// ------------- scan: per-block exclusive scan + block sums -----------------
__global__ void scan_local(const int* __restrict__ cnt, int* __restrict__ cursor,
                           int* __restrict__ bsums, int n) {
    __shared__ int tmp[SCAN_B];
    const int t = threadIdx.x;
    const int gid = blockIdx.x * SCAN_B + t;
    const int v = (gid < n) ? cnt[gid] : 0;
    tmp[t] = v;
    __syncthreads();
    for (int off = 1; off < SCAN_B; off <<= 1) {
        int u = (t >= off) ? tmp[t - off] : 0;
        __syncthreads();
        tmp[t] += u;
        __syncthreads();
    }
    if (gid < n) cursor[gid] = tmp[t] - v;
    if (t == SCAN_B - 1) bsums[blockIdx.x] = tmp[t];
}

__global__ void scan_tops(int* __restrict__ bsums, int nb) {
    __shared__ int tmp[SCAN_B];
    const int t = threadIdx.x;
    const int v = (t < nb) ? bsums[t] : 0;
    tmp[t] = v;
    __syncthreads();
    for (int off = 1; off < SCAN_B; off <<= 1) {
        int u = (t >= off) ? tmp[t - off] : 0;
        __syncthreads();
        tmp[t] += u;
        __syncthreads();
    }
    if (t < nb) bsums[t] = tmp[t] - v;  // exclusive
}

__global__ void scan_add(int* __restrict__ cursor, const int* __restrict__ bsums,
                         int n) {
    const int gid = blockIdx.x * blockDim.x + threadIdx.x;
    if (gid < n) cursor[gid] += bsums[gid >> 10];
}

// ------------- fill CSR: esrc[pos] = src, cursor -> row end ----------------
__global__ void fill_kernel(const int* __restrict__ ei, int* __restrict__ cursor,
                            int* __restrict__ esrc, int E_) {
    const int stride = gridDim.x * blockDim.x;
    for (int j = blockIdx.x * blockDim.x + threadIdx.x; j < E_; j += stride) {
        const int d = ei[E_ + j];
        const int pos = atomicAdd(&cursor[d], 1);
        esrc[pos] = ei[j];
    }
}

// ------------- fused: softmax-attention aggregate + bias + LN --------------
__global__ __launch_bounds__(256) void fused_kernel(
    const int* __restrict__ esrc, const int* __restrict__ cursor,
    const int* __restrict__ cnt, const __hip_bfloat16* __restrict__ xlb,
    const float* __restrict__ xr, const float* __restrict__ att,
    const float* __restrict__ bias, const float* __restrict__ gamma,
    const float* __restrict__ beta, float* __restrict__ out, int n) {
    const int lane = threadIdx.x & (WAVE - 1);
    const int wid = (blockIdx.x * blockDim.x + threadIdx.x) >> 6;
    const int nw = (gridDim.x * blockDim.x) >> 6;
    const float a = att[lane];
    const float bl = bias[lane];
    const float gl = gamma[lane];
    const float be = beta[lane];
    for (int node = wid; node < n; node += nw) {
        const float xrv = xr[(size_t)node * D + lane];
        const float xlv = __bfloat162float(xlb[(size_t)node * D + lane]);
        // self loop
        float v = xlv + xrv;
        v = (v > 0.f) ? v : 0.2f * v;
        float e = v * a;
#pragma unroll
        for (int off = 32; off; off >>= 1) e += __shfl_xor(e, off, WAVE);
        const float ps = __expf(e);
        float z = ps;
        float acc = ps * xlv;
        // in-edges: preload up to 64 indices coalesced, broadcast via shfl,
        // process 4 per iteration (4 independent row-gathers in flight).
        const int c = cnt[node];
        const int beg = cursor[node] - c;
        for (int base = 0; base < c; base += WAVE) {
            const int cc = min(WAVE, c - base);
            const int myi = (lane < cc) ? esrc[beg + base + lane] : 0;
            const int cl = cc - 1;
            for (int k = 0; k < cc; k += 4) {
                const int s0 = __shfl(myi, k, WAVE);
                const int s1 = __shfl(myi, min(k + 1, cl), WAVE);
                const int s2 = __shfl(myi, min(k + 2, cl), WAVE);
                const int s3 = __shfl(myi, min(k + 3, cl), WAVE);
                const float x0 = __bfloat162float(xlb[(size_t)s0 * D + lane]);
                const float x1 = __bfloat162float(xlb[(size_t)s1 * D + lane]);
                const float x2 = __bfloat162float(xlb[(size_t)s2 * D + lane]);
                const float x3 = __bfloat162float(xlb[(size_t)s3 * D + lane]);
                float v0 = x0 + xrv; v0 = (v0 > 0.f) ? v0 : 0.2f * v0;
                float v1 = x1 + xrv; v1 = (v1 > 0.f) ? v1 : 0.2f * v1;
                float v2 = x2 + xrv; v2 = (v2 > 0.f) ? v2 : 0.2f * v2;
                float v3 = x3 + xrv; v3 = (v3 > 0.f) ? v3 : 0.2f * v3;
                float e0 = v0 * a, e1 = v1 * a, e2 = v2 * a, e3 = v3 * a;
#pragma unroll
                for (int off = 32; off; off >>= 1) {
                    e0 += __shfl_xor(e0, off, WAVE);
                    e1 += __shfl_xor(e1, off, WAVE);
                    e2 += __shfl_xor(e2, off, WAVE);
                    e3 += __shfl_xor(e3, off, WAVE);
                }
                float p0 = __expf(e0);
                float p1 = (k + 1 < cc) ? __expf(e1) : 0.f;
                float p2 = (k + 2 < cc) ? __expf(e2) : 0.f;
                float p3 = (k + 3 < cc) ? __expf(e3) : 0.f;
                z += (p0 + p1) + (p2 + p3);
                acc = fmaf(p0, x0, acc);
                acc = fmaf(p1, x1, acc);
                acc = fmaf(p2, x2, acc);
                acc = fmaf(p3, x3, acc);
            }
        }
        // bias + LayerNorm
        float o = acc / z + bl;
        float s1 = o;
#pragma unroll
        for (int off = 32; off; off >>= 1) s1 += __shfl_xor(s1, off, WAVE);
        const float mu = s1 * (1.0f / D);
        const float dv = o - mu;
        float s2 = dv * dv;
#pragma unroll
        for (int off = 32; off; off >>= 1) s2 += __shfl_xor(s2, off, WAVE);
        const float var = s2 * (1.0f / D);
        const float rs = rsqrtf(var + 1e-5f);
        out[(size_t)node * D + lane] = dv * rs * gl + be;
    }
}

extern "C" void kernel_launch(void* const* d_in, const int* in_sizes, int n_in,
                              void* d_out, int out_size, void* d_ws, size_t ws_size,
                              hipStream_t stream) {
    const float* x = (const float*)d_in[0];
    const int* ei = (const int*)d_in[1];
    const float* Wl = (const float*)d_in[2];
    const float* bl = (const float*)d_in[3];
    const float* Wr = (const float*)d_in[4];
    const float* br = (const float*)d_in[5];
    const float* att = (const float*)d_in[6];
    const float* bias = (const float*)d_in[7];
    const float* gamma = (const float*)d_in[8];
    const float* beta = (const float*)d_in[9];

    const int n = in_sizes[0] / D;   // 100000
    const int E_ = in_sizes[1] / 2;  // 1000000
    const int nb = (n + SCAN_B - 1) / SCAN_B;

    char* ws = (char*)d_ws;
    __hip_bfloat16* xlb = (__hip_bfloat16*)ws;            // n*D bf16
    float* xr = (float*)(ws + ((size_t)n * D * 2 + 255 & ~255ul)); // n*D f32
    int* cnt = (int*)((char*)xr + (size_t)n * D * 4);     // n
    int* cursor = cnt + n;                                // n
    int* bsums = cursor + n;                              // nb
    int* esrc = bsums + ((nb + 63) & ~63);                // E_

    hipMemsetAsync(cnt, 0, (size_t)n * sizeof(int), stream);

    transform_hist_kernel<<<1536, 256, 0, stream>>>(x, Wl, bl, Wr, br, xlb, xr,
                                                    ei, cnt, n, E_, 1024);
    scan_local<<<nb, SCAN_B, 0, stream>>>(cnt, cursor, bsums, n);
    scan_tops<<<1, SCAN_B, 0, stream>>>(bsums, nb);
    scan_add<<<(n + 255) / 256, 256, 0, stream>>>(cursor, bsums, n);
    fill_kernel<<<2048, 256, 0, stream>>>(ei, cursor, esrc, E_);
    fused_kernel<<<2048, 256, 0, stream>>>(esrc, cursor, cnt, xlb, xr, att,
                                           bias, gamma, beta, (float*)d_out, n);
}

// Round 5
// 234.615 us; speedup vs baseline: 2.1879x; 1.2259x over previous
//
#include <hip/hip_runtime.h>
#include <hip/hip_bf16.h>

#define D 64
#define WAVE 64
#define SCAN_B 1024
#define NB 8

// ------------- K1: transform (blocks [0,tblocks)) + dst histogram ----------
__global__ __launch_bounds__(256) void transform_hist_kernel(
    const float* __restrict__ x, const float* __restrict__ Wl,
    const float* __restrict__ bl, const float* __restrict__ Wr,
    const float* __restrict__ br, __hip_bfloat16* __restrict__ xlb,
    float* __restrict__ xr, const int* __restrict__ ei,
    int* __restrict__ cnt, int n, int E_, int tblocks) {
    __shared__ float sWl[D * D];
    __shared__ float sWr[D * D];
    if ((int)blockIdx.x < tblocks) {
        for (int i = threadIdx.x; i < D * D; i += blockDim.x) {
            sWl[i] = Wl[i];
            sWr[i] = Wr[i];
        }
        __syncthreads();
        const int lane = threadIdx.x & (WAVE - 1);
        const int wid = (blockIdx.x * blockDim.x + threadIdx.x) >> 6;
        const int nw = (tblocks * blockDim.x) >> 6;
        const float bll = bl[lane];
        const float brl = br[lane];
        const int ngrp = (n + NB - 1) / NB;
        for (int g = wid; g < ngrp; g += nw) {
            const int node0 = g * NB;
            float xk[NB], accl[NB], accr[NB];
#pragma unroll
            for (int t = 0; t < NB; ++t) {
                const int nd = min(node0 + t, n - 1);
                xk[t] = x[(size_t)nd * D + lane];
                accl[t] = bll;
                accr[t] = brl;
            }
#pragma unroll 4
            for (int k = 0; k < D; ++k) {
                const float wl = sWl[k * D + lane];
                const float wr = sWr[k * D + lane];
#pragma unroll
                for (int t = 0; t < NB; ++t) {
                    const float xv = __shfl(xk[t], k, WAVE);
                    accl[t] = fmaf(xv, wl, accl[t]);
                    accr[t] = fmaf(xv, wr, accr[t]);
                }
            }
#pragma unroll
            for (int t = 0; t < NB; ++t) {
                if (node0 + t < n) {
                    const size_t off = (size_t)(node0 + t) * D + lane;
                    xlb[off] = __float2bfloat16(accl[t]);
                    xr[off] = accr[t];
                }
            }
        }
    } else {
        const int tid = (blockIdx.x - tblocks) * blockDim.x + threadIdx.x;
        const int stride = (gridDim.x - tblocks) * blockDim.x;
        for (int j = tid; j < E_; j += stride)
            atomicAdd(&cnt[ei[E_ + j]], 1);
    }
}

// ------------- scan: per-block exclusive scan + block sums -----------------
__global__ void scan_local(const int* __restrict__ cnt, int* __restrict__ cursor,
                           int* __restrict__ bsums, int n) {
    __shared__ int tmp[SCAN_B];
    const int t = threadIdx.x;
    const int gid = blockIdx.x * SCAN_B + t;
    const int v = (gid < n) ? cnt[gid] : 0;
    tmp[t] = v;
    __syncthreads();
    for (int off = 1; off < SCAN_B; off <<= 1) {
        int u = (t >= off) ? tmp[t - off] : 0;
        __syncthreads();
        tmp[t] += u;
        __syncthreads();
    }
    if (gid < n) cursor[gid] = tmp[t] - v;
    if (t == SCAN_B - 1) bsums[blockIdx.x] = tmp[t];
}

__global__ void scan_tops(int* __restrict__ bsums, int nb) {
    __shared__ int tmp[SCAN_B];
    const int t = threadIdx.x;
    const int v = (t < nb) ? bsums[t] : 0;
    tmp[t] = v;
    __syncthreads();
    for (int off = 1; off < SCAN_B; off <<= 1) {
        int u = (t >= off) ? tmp[t - off] : 0;
        __syncthreads();
        tmp[t] += u;
        __syncthreads();
    }
    if (t < nb) bsums[t] = tmp[t] - v;  // exclusive
}

__global__ void scan_add(int* __restrict__ cursor, const int* __restrict__ bsums,
                         int n) {
    const int gid = blockIdx.x * blockDim.x + threadIdx.x;
    if (gid < n) cursor[gid] += bsums[gid >> 10];
}

// ------------- fill CSR: esrc[pos] = src, cursor -> row end ----------------
__global__ void fill_kernel(const int* __restrict__ ei, int* __restrict__ cursor,
                            int* __restrict__ esrc, int E_) {
    const int stride = gridDim.x * blockDim.x;
    for (int j = blockIdx.x * blockDim.x + threadIdx.x; j < E_; j += stride) {
        const int d = ei[E_ + j];
        const int pos = atomicAdd(&cursor[d], 1);
        esrc[pos] = ei[j];
    }
}

// ------------- fused: softmax-attention aggregate + bias + LN --------------
// Wave layout: 4 groups of 16 lanes. Each group processes one edge at a time;
// within a group, lane `sub` owns dims [4*sub, 4*sub+4). One bf16x4 (8B) load
// per lane per edge = full 128B row per group. Logit dot: 4 in-lane FMAs +
// 4-round 16-lane butterfly (shared by all 4 concurrent edges). Self loop is
// folded in as virtual edge index c (any gidx >= c maps src -> node).
__global__ __launch_bounds__(256) void fused_kernel(
    const int* __restrict__ esrc, const int* __restrict__ cursor,
    const int* __restrict__ cnt, const __hip_bfloat16* __restrict__ xlb,
    const float* __restrict__ xr, const float* __restrict__ att,
    const float* __restrict__ bias, const float* __restrict__ gamma,
    const float* __restrict__ beta, float* __restrict__ out, int n) {
    const int lane = threadIdx.x & (WAVE - 1);
    const int sub = lane & 15;   // dim slice
    const int grp = lane >> 4;   // edge group 0..3
    const int wid = (blockIdx.x * blockDim.x + threadIdx.x) >> 6;
    const int nw = (gridDim.x * blockDim.x) >> 6;

    const float4 a4 = reinterpret_cast<const float4*>(att)[sub];
    const float4 b4 = reinterpret_cast<const float4*>(bias)[sub];
    const float4 g4 = reinterpret_cast<const float4*>(gamma)[sub];
    const float4 be4 = reinterpret_cast<const float4*>(beta)[sub];

    for (int node = wid; node < n; node += nw) {
        const float4 xr4 = reinterpret_cast<const float4*>(xr + (size_t)node * D)[sub];
        const int c = cnt[node];
        const int beg = cursor[node] - c;
        const int total = c + 1;  // + self loop

        float zacc = 0.f;
        float acc0 = 0.f, acc1 = 0.f, acc2 = 0.f, acc3 = 0.f;

        for (int base = 0; base < total; base += WAVE) {
            const int cc = min(WAVE, total - base);
            const int gidx = base + lane;
            const int myi = (gidx < c) ? esrc[beg + gidx] : node;

            for (int k = 0; k < cc; k += 8) {
                const int idxA = k + grp;
                const int idxB = k + 4 + grp;
                const bool vA = idxA < cc;
                const bool vB = idxB < cc;
                const int sA = __shfl(myi, vA ? idxA : 0, WAVE);
                const int sB = __shfl(myi, vB ? idxB : 0, WAVE);
                const uint2 rA = *reinterpret_cast<const uint2*>(
                    xlb + (size_t)sA * D + 4 * sub);
                const uint2 rB = *reinterpret_cast<const uint2*>(
                    xlb + (size_t)sB * D + 4 * sub);

                // ---- edge A ----
                {
                    const float x0 = __uint_as_float(rA.x << 16);
                    const float x1 = __uint_as_float(rA.x & 0xffff0000u);
                    const float x2 = __uint_as_float(rA.y << 16);
                    const float x3 = __uint_as_float(rA.y & 0xffff0000u);
                    float v0 = x0 + xr4.x; v0 = (v0 > 0.f) ? v0 : 0.2f * v0;
                    float v1 = x1 + xr4.y; v1 = (v1 > 0.f) ? v1 : 0.2f * v1;
                    float v2 = x2 + xr4.z; v2 = (v2 > 0.f) ? v2 : 0.2f * v2;
                    float v3 = x3 + xr4.w; v3 = (v3 > 0.f) ? v3 : 0.2f * v3;
                    float t = v0 * a4.x;
                    t = fmaf(v1, a4.y, t);
                    t = fmaf(v2, a4.z, t);
                    t = fmaf(v3, a4.w, t);
#pragma unroll
                    for (int off = 1; off < 16; off <<= 1)
                        t += __shfl_xor(t, off, WAVE);
                    const float p = vA ? __expf(t) : 0.f;
                    zacc += p;
                    acc0 = fmaf(p, x0, acc0);
                    acc1 = fmaf(p, x1, acc1);
                    acc2 = fmaf(p, x2, acc2);
                    acc3 = fmaf(p, x3, acc3);
                }
                // ---- edge B ----
                {
                    const float x0 = __uint_as_float(rB.x << 16);
                    const float x1 = __uint_as_float(rB.x & 0xffff0000u);
                    const float x2 = __uint_as_float(rB.y << 16);
                    const float x3 = __uint_as_float(rB.y & 0xffff0000u);
                    float v0 = x0 + xr4.x; v0 = (v0 > 0.f) ? v0 : 0.2f * v0;
                    float v1 = x1 + xr4.y; v1 = (v1 > 0.f) ? v1 : 0.2f * v1;
                    float v2 = x2 + xr4.z; v2 = (v2 > 0.f) ? v2 : 0.2f * v2;
                    float v3 = x3 + xr4.w; v3 = (v3 > 0.f) ? v3 : 0.2f * v3;
                    float t = v0 * a4.x;
                    t = fmaf(v1, a4.y, t);
                    t = fmaf(v2, a4.z, t);
                    t = fmaf(v3, a4.w, t);
#pragma unroll
                    for (int off = 1; off < 16; off <<= 1)
                        t += __shfl_xor(t, off, WAVE);
                    const float p = vB ? __expf(t) : 0.f;
                    zacc += p;
                    acc0 = fmaf(p, x0, acc0);
                    acc1 = fmaf(p, x1, acc1);
                    acc2 = fmaf(p, x2, acc2);
                    acc3 = fmaf(p, x3, acc3);
                }
            }
        }
        // cross-group combine (sums the 4 groups' edge sets)
#pragma unroll
        for (int off = 16; off < 64; off <<= 1) {
            zacc += __shfl_xor(zacc, off, WAVE);
            acc0 += __shfl_xor(acc0, off, WAVE);
            acc1 += __shfl_xor(acc1, off, WAVE);
            acc2 += __shfl_xor(acc2, off, WAVE);
            acc3 += __shfl_xor(acc3, off, WAVE);
        }
        const float inv = 1.f / zacc;
        const float o0 = fmaf(acc0, inv, b4.x);
        const float o1 = fmaf(acc1, inv, b4.y);
        const float o2 = fmaf(acc2, inv, b4.z);
        const float o3 = fmaf(acc3, inv, b4.w);
        // LayerNorm over 64 dims (16 lanes x 4)
        float s1 = (o0 + o1) + (o2 + o3);
#pragma unroll
        for (int off = 1; off < 16; off <<= 1) s1 += __shfl_xor(s1, off, WAVE);
        const float mu = s1 * (1.0f / D);
        const float d0 = o0 - mu, d1 = o1 - mu, d2 = o2 - mu, d3 = o3 - mu;
        float s2 = (d0 * d0 + d1 * d1) + (d2 * d2 + d3 * d3);
#pragma unroll
        for (int off = 1; off < 16; off <<= 1) s2 += __shfl_xor(s2, off, WAVE);
        const float rs = rsqrtf(s2 * (1.0f / D) + 1e-5f);
        if (grp == 0) {
            float4 r;
            r.x = d0 * rs * g4.x + be4.x;
            r.y = d1 * rs * g4.y + be4.y;
            r.z = d2 * rs * g4.z + be4.z;
            r.w = d3 * rs * g4.w + be4.w;
            reinterpret_cast<float4*>(out + (size_t)node * D)[sub] = r;
        }
    }
}

extern "C" void kernel_launch(void* const* d_in, const int* in_sizes, int n_in,
                              void* d_out, int out_size, void* d_ws, size_t ws_size,
                              hipStream_t stream) {
    const float* x = (const float*)d_in[0];
    const int* ei = (const int*)d_in[1];
    const float* Wl = (const float*)d_in[2];
    const float* bl = (const float*)d_in[3];
    const float* Wr = (const float*)d_in[4];
    const float* br = (const float*)d_in[5];
    const float* att = (const float*)d_in[6];
    const float* bias = (const float*)d_in[7];
    const float* gamma = (const float*)d_in[8];
    const float* beta = (const float*)d_in[9];

    const int n = in_sizes[0] / D;   // 100000
    const int E_ = in_sizes[1] / 2;  // 1000000
    const int nb = (n + SCAN_B - 1) / SCAN_B;

    char* ws = (char*)d_ws;
    __hip_bfloat16* xlb = (__hip_bfloat16*)ws;                      // n*D bf16
    float* xr = (float*)(ws + (((size_t)n * D * 2 + 255) & ~255ul)); // n*D f32
    int* cnt = (int*)((char*)xr + (size_t)n * D * 4);               // n
    int* cursor = cnt + n;                                          // n
    int* bsums = cursor + n;                                        // nb
    int* esrc = bsums + ((nb + 63) & ~63);                          // E_

    hipMemsetAsync(cnt, 0, (size_t)n * sizeof(int), stream);

    transform_hist_kernel<<<1536, 256, 0, stream>>>(x, Wl, bl, Wr, br, xlb, xr,
                                                    ei, cnt, n, E_, 1024);
    scan_local<<<nb, SCAN_B, 0, stream>>>(cnt, cursor, bsums, n);
    scan_tops<<<1, SCAN_B, 0, stream>>>(bsums, nb);
    scan_add<<<(n + 255) / 256, 256, 0, stream>>>(cursor, bsums, n);
    fill_kernel<<<2048, 256, 0, stream>>>(ei, cursor, esrc, E_);
    fused_kernel<<<2048, 256, 0, stream>>>(esrc, cursor, cnt, xlb, xr, att,
                                           bias, gamma, beta, (float*)d_out, n);
}

// Round 6
// 224.349 us; speedup vs baseline: 2.2880x; 1.0458x over previous
//
#include <hip/hip_runtime.h>
#include <hip/hip_bf16.h>

#define D 64
#define WAVE 64
#define SCAN_B 1024
#define NB 8

// ------------- K1: transform (blocks [0,tblocks)) + dst histogram ----------
// Transform: W columns live in VGPRs (wl[64]/wr[64], statically indexed by
// full unroll). x row values are wave-uniform -> readfirstlane'd base makes
// the compiler emit scalar (SMEM) loads. Inner loop = pure v_fma. No LDS.
__global__ __launch_bounds__(256) void transform_hist_kernel(
    const float* __restrict__ x, const float* __restrict__ Wl,
    const float* __restrict__ bl, const float* __restrict__ Wr,
    const float* __restrict__ br, __hip_bfloat16* __restrict__ xlb,
    float* __restrict__ xr, const int* __restrict__ ei,
    int* __restrict__ cnt, int n, int E_, int tblocks) {
    if ((int)blockIdx.x < tblocks) {
        const int lane = threadIdx.x & (WAVE - 1);
        float wl[D], wr[D];
#pragma unroll
        for (int k = 0; k < D; ++k) {
            wl[k] = Wl[k * D + lane];   // coalesced 256B per k
            wr[k] = Wr[k * D + lane];
        }
        const float bll = bl[lane];
        const float brl = br[lane];
        const int wid = (blockIdx.x * blockDim.x + threadIdx.x) >> 6;
        const int nw = (tblocks * blockDim.x) >> 6;
        const int ngrp = (n + NB - 1) / NB;
        for (int g = wid; g < ngrp; g += nw) {
            const int node0 = __builtin_amdgcn_readfirstlane(g * NB);
            const float* __restrict__ xb = x + (size_t)node0 * D;
            float accl[NB], accr[NB];
#pragma unroll
            for (int t = 0; t < NB; ++t) { accl[t] = bll; accr[t] = brl; }
            if (node0 + NB <= n) {
#pragma unroll
                for (int kc = 0; kc < D; kc += 4) {
                    float xs[NB][4];
#pragma unroll
                    for (int t = 0; t < NB; ++t)
#pragma unroll
                        for (int j = 0; j < 4; ++j)
                            xs[t][j] = xb[t * D + kc + j];  // uniform -> s_load
#pragma unroll
                    for (int j = 0; j < 4; ++j)
#pragma unroll
                        for (int t = 0; t < NB; ++t) {
                            accl[t] = fmaf(xs[t][j], wl[kc + j], accl[t]);
                            accr[t] = fmaf(xs[t][j], wr[kc + j], accr[t]);
                        }
                }
#pragma unroll
                for (int t = 0; t < NB; ++t) {
                    const size_t off = (size_t)(node0 + t) * D + lane;
                    xlb[off] = __float2bfloat16(accl[t]);
                    xr[off] = accr[t];
                }
            } else {
                for (int t = 0; t < NB && node0 + t < n; ++t) {
                    float al = bll, ar = brl;
#pragma unroll
                    for (int k = 0; k < D; ++k) {
                        const float xv = xb[t * D + k];
                        al = fmaf(xv, wl[k], al);
                        ar = fmaf(xv, wr[k], ar);
                    }
                    const size_t off = (size_t)(node0 + t) * D + lane;
                    xlb[off] = __float2bfloat16(al);
                    xr[off] = ar;
                }
            }
        }
    } else {
        const int tid = (blockIdx.x - tblocks) * blockDim.x + threadIdx.x;
        const int stride = (gridDim.x - tblocks) * blockDim.x;
        for (int j = tid; j < E_; j += stride)
            atomicAdd(&cnt[ei[E_ + j]], 1);
    }
}

// ------------- scan: per-block exclusive scan + block sums -----------------
__global__ void scan_local(const int* __restrict__ cnt, int* __restrict__ cursor,
                           int* __restrict__ bsums, int n) {
    __shared__ int tmp[SCAN_B];
    const int t = threadIdx.x;
    const int gid = blockIdx.x * SCAN_B + t;
    const int v = (gid < n) ? cnt[gid] : 0;
    tmp[t] = v;
    __syncthreads();
    for (int off = 1; off < SCAN_B; off <<= 1) {
        int u = (t >= off) ? tmp[t - off] : 0;
        __syncthreads();
        tmp[t] += u;
        __syncthreads();
    }
    if (gid < n) cursor[gid] = tmp[t] - v;  // block-local exclusive
    if (t == SCAN_B - 1) bsums[blockIdx.x] = tmp[t];
}

__global__ void scan_tops(int* __restrict__ bsums, int nb) {
    __shared__ int tmp[SCAN_B];
    const int t = threadIdx.x;
    const int v = (t < nb) ? bsums[t] : 0;
    tmp[t] = v;
    __syncthreads();
    for (int off = 1; off < SCAN_B; off <<= 1) {
        int u = (t >= off) ? tmp[t - off] : 0;
        __syncthreads();
        tmp[t] += u;
        __syncthreads();
    }
    if (t < nb) bsums[t] = tmp[t] - v;  // exclusive block bases
}

// ------------- fill CSR: esrc[pos] = src (cursor stays block-local) --------
__global__ void fill_kernel(const int* __restrict__ ei, int* __restrict__ cursor,
                            const int* __restrict__ bsums,
                            int* __restrict__ esrc, int E_) {
    const int stride = gridDim.x * blockDim.x;
    for (int j = blockIdx.x * blockDim.x + threadIdx.x; j < E_; j += stride) {
        const int d = ei[E_ + j];
        const int pos = bsums[d >> 10] + atomicAdd(&cursor[d], 1);
        esrc[pos] = ei[j];
    }
}

// ------------- fused: softmax-attention aggregate + bias + LN --------------
__global__ __launch_bounds__(256) void fused_kernel(
    const int* __restrict__ esrc, const int* __restrict__ cursor,
    const int* __restrict__ bsums, const int* __restrict__ cnt,
    const __hip_bfloat16* __restrict__ xlb, const float* __restrict__ xr,
    const float* __restrict__ att, const float* __restrict__ bias,
    const float* __restrict__ gamma, const float* __restrict__ beta,
    float* __restrict__ out, int n) {
    const int lane = threadIdx.x & (WAVE - 1);
    const int sub = lane & 15;   // dim slice
    const int grp = lane >> 4;   // edge group 0..3
    const int wid = (blockIdx.x * blockDim.x + threadIdx.x) >> 6;
    const int nw = (gridDim.x * blockDim.x) >> 6;

    const float4 a4 = reinterpret_cast<const float4*>(att)[sub];
    const float4 b4 = reinterpret_cast<const float4*>(bias)[sub];
    const float4 g4 = reinterpret_cast<const float4*>(gamma)[sub];
    const float4 be4 = reinterpret_cast<const float4*>(beta)[sub];

    for (int node = wid; node < n; node += nw) {
        const float4 xr4 = reinterpret_cast<const float4*>(xr + (size_t)node * D)[sub];
        const int c = cnt[node];
        // after fill: cursor[node] = local_start + c; global beg:
        const int beg = bsums[node >> 10] + cursor[node] - c;
        const int total = c + 1;  // + self loop

        float zacc = 0.f;
        float acc0 = 0.f, acc1 = 0.f, acc2 = 0.f, acc3 = 0.f;

        for (int base = 0; base < total; base += WAVE) {
            const int cc = min(WAVE, total - base);
            const int gidx = base + lane;
            const int myi = (gidx < c) ? esrc[beg + gidx] : node;

            for (int k = 0; k < cc; k += 8) {
                const int idxA = k + grp;
                const int idxB = k + 4 + grp;
                const bool vA = idxA < cc;
                const bool vB = idxB < cc;
                const int sA = __shfl(myi, vA ? idxA : 0, WAVE);
                const int sB = __shfl(myi, vB ? idxB : 0, WAVE);
                const uint2 rA = *reinterpret_cast<const uint2*>(
                    xlb + (size_t)sA * D + 4 * sub);
                const uint2 rB = *reinterpret_cast<const uint2*>(
                    xlb + (size_t)sB * D + 4 * sub);

                // ---- edge A ----
                {
                    const float x0 = __uint_as_float(rA.x << 16);
                    const float x1 = __uint_as_float(rA.x & 0xffff0000u);
                    const float x2 = __uint_as_float(rA.y << 16);
                    const float x3 = __uint_as_float(rA.y & 0xffff0000u);
                    float v0 = x0 + xr4.x; v0 = (v0 > 0.f) ? v0 : 0.2f * v0;
                    float v1 = x1 + xr4.y; v1 = (v1 > 0.f) ? v1 : 0.2f * v1;
                    float v2 = x2 + xr4.z; v2 = (v2 > 0.f) ? v2 : 0.2f * v2;
                    float v3 = x3 + xr4.w; v3 = (v3 > 0.f) ? v3 : 0.2f * v3;
                    float t = v0 * a4.x;
                    t = fmaf(v1, a4.y, t);
                    t = fmaf(v2, a4.z, t);
                    t = fmaf(v3, a4.w, t);
#pragma unroll
                    for (int off = 1; off < 16; off <<= 1)
                        t += __shfl_xor(t, off, WAVE);
                    const float p = vA ? __expf(t) : 0.f;
                    zacc += p;
                    acc0 = fmaf(p, x0, acc0);
                    acc1 = fmaf(p, x1, acc1);
                    acc2 = fmaf(p, x2, acc2);
                    acc3 = fmaf(p, x3, acc3);
                }
                // ---- edge B ----
                {
                    const float x0 = __uint_as_float(rB.x << 16);
                    const float x1 = __uint_as_float(rB.x & 0xffff0000u);
                    const float x2 = __uint_as_float(rB.y << 16);
                    const float x3 = __uint_as_float(rB.y & 0xffff0000u);
                    float v0 = x0 + xr4.x; v0 = (v0 > 0.f) ? v0 : 0.2f * v0;
                    float v1 = x1 + xr4.y; v1 = (v1 > 0.f) ? v1 : 0.2f * v1;
                    float v2 = x2 + xr4.z; v2 = (v2 > 0.f) ? v2 : 0.2f * v2;
                    float v3 = x3 + xr4.w; v3 = (v3 > 0.f) ? v3 : 0.2f * v3;
                    float t = v0 * a4.x;
                    t = fmaf(v1, a4.y, t);
                    t = fmaf(v2, a4.z, t);
                    t = fmaf(v3, a4.w, t);
#pragma unroll
                    for (int off = 1; off < 16; off <<= 1)
                        t += __shfl_xor(t, off, WAVE);
                    const float p = vB ? __expf(t) : 0.f;
                    zacc += p;
                    acc0 = fmaf(p, x0, acc0);
                    acc1 = fmaf(p, x1, acc1);
                    acc2 = fmaf(p, x2, acc2);
                    acc3 = fmaf(p, x3, acc3);
                }
            }
        }
        // cross-group combine
#pragma unroll
        for (int off = 16; off < 64; off <<= 1) {
            zacc += __shfl_xor(zacc, off, WAVE);
            acc0 += __shfl_xor(acc0, off, WAVE);
            acc1 += __shfl_xor(acc1, off, WAVE);
            acc2 += __shfl_xor(acc2, off, WAVE);
            acc3 += __shfl_xor(acc3, off, WAVE);
        }
        const float inv = 1.f / zacc;
        const float o0 = fmaf(acc0, inv, b4.x);
        const float o1 = fmaf(acc1, inv, b4.y);
        const float o2 = fmaf(acc2, inv, b4.z);
        const float o3 = fmaf(acc3, inv, b4.w);
        float s1 = (o0 + o1) + (o2 + o3);
#pragma unroll
        for (int off = 1; off < 16; off <<= 1) s1 += __shfl_xor(s1, off, WAVE);
        const float mu = s1 * (1.0f / D);
        const float d0 = o0 - mu, d1 = o1 - mu, d2 = o2 - mu, d3 = o3 - mu;
        float s2 = (d0 * d0 + d1 * d1) + (d2 * d2 + d3 * d3);
#pragma unroll
        for (int off = 1; off < 16; off <<= 1) s2 += __shfl_xor(s2, off, WAVE);
        const float rs = rsqrtf(s2 * (1.0f / D) + 1e-5f);
        if (grp == 0) {
            float4 r;
            r.x = d0 * rs * g4.x + be4.x;
            r.y = d1 * rs * g4.y + be4.y;
            r.z = d2 * rs * g4.z + be4.z;
            r.w = d3 * rs * g4.w + be4.w;
            reinterpret_cast<float4*>(out + (size_t)node * D)[sub] = r;
        }
    }
}

extern "C" void kernel_launch(void* const* d_in, const int* in_sizes, int n_in,
                              void* d_out, int out_size, void* d_ws, size_t ws_size,
                              hipStream_t stream) {
    const float* x = (const float*)d_in[0];
    const int* ei = (const int*)d_in[1];
    const float* Wl = (const float*)d_in[2];
    const float* bl = (const float*)d_in[3];
    const float* Wr = (const float*)d_in[4];
    const float* br = (const float*)d_in[5];
    const float* att = (const float*)d_in[6];
    const float* bias = (const float*)d_in[7];
    const float* gamma = (const float*)d_in[8];
    const float* beta = (const float*)d_in[9];

    const int n = in_sizes[0] / D;   // 100000
    const int E_ = in_sizes[1] / 2;  // 1000000
    const int nb = (n + SCAN_B - 1) / SCAN_B;

    char* ws = (char*)d_ws;
    __hip_bfloat16* xlb = (__hip_bfloat16*)ws;                       // n*D bf16
    float* xr = (float*)(ws + (((size_t)n * D * 2 + 255) & ~255ul)); // n*D f32
    int* cnt = (int*)((char*)xr + (size_t)n * D * 4);                // n
    int* cursor = cnt + n;                                           // n
    int* bsums = cursor + n;                                         // nb
    int* esrc = bsums + ((nb + 63) & ~63);                           // E_

    hipMemsetAsync(cnt, 0, (size_t)n * sizeof(int), stream);

    transform_hist_kernel<<<2048, 256, 0, stream>>>(x, Wl, bl, Wr, br, xlb, xr,
                                                    ei, cnt, n, E_, 1024);
    scan_local<<<nb, SCAN_B, 0, stream>>>(cnt, cursor, bsums, n);
    scan_tops<<<1, SCAN_B, 0, stream>>>(bsums, nb);
    fill_kernel<<<2048, 256, 0, stream>>>(ei, cursor, bsums, esrc, E_);
    fused_kernel<<<2048, 256, 0, stream>>>(esrc, cursor, bsums, cnt, xlb, xr,
                                           att, bias, gamma, beta,
                                           (float*)d_out, n);
}